// Round 12
// baseline (257.574 us; speedup 1.0000x reference)
//
#include <hip/hip_runtime.h>
#include <hip/hip_bf16.h>
#include <stdint.h>

// Problem dims
#define B_ROWS 8192
#define D_DIM  1024
#define C_CLS  1000
#define K_PROT 8
#define N_PAD  8064          // 63 * 128 zero-padded prototype columns
#define BM2    256
#define BN2    128
#define BKT    64            // K-tile depth (elements)
#define NTI    16            // D_DIM / BKT

typedef __attribute__((ext_vector_type(8))) short  short8;   // 8 bf16
typedef __attribute__((ext_vector_type(4))) float  f32x4;    // MFMA acc

// --- helpers -------------------------------------------------------------

__device__ __forceinline__ ushort f2bf(float f) {
    union { float f; uint32_t u; } v; v.f = f;
    uint32_t u = v.u;
    return (ushort)((u + 0x7fffu + ((u >> 16) & 1u)) >> 16);
}

typedef __attribute__((address_space(1))) void gv_t;
typedef __attribute__((address_space(3))) void lv_t;

__device__ __forceinline__ void gload_lds16(const void* g, void* l) {
    // async global->LDS, 16B/lane; LDS dest = wave-uniform base + lane*16
    __builtin_amdgcn_global_load_lds((gv_t*)g, (lv_t*)l, 16, 0, 0);
}

__device__ __forceinline__ float waveReduceSum(float s) {
    #pragma unroll
    for (int m = 32; m >= 1; m >>= 1) s += __shfl_xor(s, m);
    return s;
}

// --- kernel 1: fused prep -------------------------------------------------
// blocks 0..8191:       x row b -> bf16 + cx2 = sum(x^2)
// blocks 8192..16255:   weight_v -> normalized bf16, PERMUTED + padded
// Column permutation (R6-verified): physical col P: gpan=P>>6 (64-col
// panel), ni=(P>>4)&3, cc=P&15; class = gpan*8 + (cc&7), k = ni+4*(cc>>3)
// -> all 8 k's of a class land in lane pair (lane, lane^8) of the epilogue.

__global__ __launch_bounds__(256) void prep(const float* __restrict__ x,
                                            const float* __restrict__ wv,
                                            ushort* __restrict__ xb,
                                            ushort* __restrict__ zb,
                                            float* __restrict__ cx2) {
    const int t = threadIdx.x;
    __shared__ float red[4];

    if ((int)blockIdx.x < B_ROWS) {
        const int b = blockIdx.x;
        const float4 v = ((const float4*)(x + (size_t)b * D_DIM))[t];
        ushort4 o;
        o.x = f2bf(v.x); o.y = f2bf(v.y); o.z = f2bf(v.z); o.w = f2bf(v.w);
        ((ushort4*)(xb + (size_t)b * D_DIM))[t] = o;
        float s = v.x*v.x + v.y*v.y + v.z*v.z + v.w*v.w;
        s = waveReduceSum(s);
        if ((t & 63) == 0) red[t >> 6] = s;
        __syncthreads();
        if (t == 0) cx2[b] = red[0] + red[1] + red[2] + red[3];
        return;
    }

    const int P    = blockIdx.x - B_ROWS;       // 0..N_PAD-1
    const int gpan = P >> 6;
    const int ni   = (P >> 4) & 3;
    const int cc   = P & 15;
    const int cls  = gpan * 8 + (cc & 7);
    const int k    = ni + ((cc >> 3) << 2);

    if (cls >= C_CLS) {
        ((ushort4*)(zb + (size_t)P * D_DIM))[t] = make_ushort4(0, 0, 0, 0);
        return;
    }
    const int n = cls * K_PROT + k;
    const float4 v = ((const float4*)(wv + (size_t)n * D_DIM))[t];
    float s = v.x*v.x + v.y*v.y + v.z*v.z + v.w*v.w;
    s = waveReduceSum(s);
    if ((t & 63) == 0) red[t >> 6] = s;
    __syncthreads();
    const float n2 = red[0] + red[1] + red[2] + red[3];
    const float rn = 1.0f / fmaxf(sqrtf(n2), 1e-15f);
    ushort4 o;
    o.x = f2bf(v.x * rn); o.y = f2bf(v.y * rn);
    o.z = f2bf(v.z * rn); o.w = f2bf(v.w * rn);
    ((ushort4*)(zb + (size_t)P * D_DIM))[t] = o;
}

// --- kernel 2: 256x128 block, 4 waves (128x64 each) -----------------------
// R6 A-path verbatim (LDS staging + proven 0-conflict swizzle + 2-barrier
// loop). NEW: B-fragments read DIRECTLY from global (L2-resident: the
// 16KB/tile B panel is shared by 32 consecutive blocks). Removes B staging
// (4 gloads), B LDS writes (16KB/tile) and B LDS reads (32KB/tile) = -33%
// LDS traffic; B addressing is per-lane so no swizzle needed. LDS 48->32KB.

__global__ __launch_bounds__(256, 2) void gemm_epi(
        const ushort* __restrict__ A,    // [B_ROWS][D_DIM] bf16 (x)
        const ushort* __restrict__ Bz,   // [N_PAD][D_DIM] bf16 (permuted z)
        const float*  __restrict__ cx2g, // [B_ROWS]
        const float*  __restrict__ wgl,  // [C_CLS]
        const float*  __restrict__ gamma_p,
        float*        __restrict__ out)  // [B_ROWS][C_CLS]
{
    __shared__ __attribute__((aligned(16))) ushort sA[BM2 * BKT]; // 32 KB

    const int tid  = threadIdx.x;
    const int lane = tid & 63;
    const int w    = tid >> 6;        // wave 0..3
    const int wm   = w >> 1;          // 0..1 : 128 output rows each
    const int wn   = w & 1;           // 0..1 : 64 output cols each

    // bm fastest: 32 consecutive blocks share one B-panel (256 KB L2-hot)
    const int bm = blockIdx.x & 31;
    const int bn = blockIdx.x >> 5;   // 0..62
    const int m0 = bm * BM2;
    const int n0 = bn * BN2;

    // A staging: thread covers row (tid>>3) within each 32-row group; source
    // col-group = (lane&7) ^ (row&7)  [T2 swizzle, source side; row&7=lane>>3]
    const int stCol = ((lane & 7) ^ (lane >> 3)) * 8;
    const ushort* aS = A + (size_t)(m0 + (tid >> 3)) * D_DIM + stCol;

    // A fragment reads (128 B rows; R6-proven 0-conflict swizzle)
    const int swz0 = ((      (lane >> 4) * 16) ^ ((lane & 7) << 4));
    const int swz1 = ((64 + ((lane >> 4) * 16)) ^ ((lane & 7) << 4));
    const char* sAb = (const char*)sA + (wm * 128 + (lane & 15)) * 128;

    // B fragment source: per-lane global address (no LDS round-trip).
    // b[ni] (MFMA B-operand, 16x16x32): lane reads row n0+wn*64+ni*16+
    // (lane&15), elements kk*32+(lane>>4)*8 .. +8 of the K-tile.
    const ushort* bG = Bz + (size_t)(n0 + wn * 64 + (lane & 15)) * D_DIM
                          + ((lane >> 4) * 8);

    f32x4 acc[8][4];
    #pragma unroll
    for (int mi = 0; mi < 8; ++mi)
        #pragma unroll
        for (int ni = 0; ni < 4; ++ni)
            acc[mi][ni] = (f32x4)(0.0f);

    for (int t = 0; t < NTI; ++t) {
        const int k0 = t * BKT;
        // stage A only: 8 x 32-row groups
        #pragma unroll
        for (int i = 0; i < 8; ++i)
            gload_lds16(aS + (size_t)i * 32 * D_DIM + k0,
                        (char*)sA + i * 4096 + w * 1024);
        __syncthreads();

        // B fragments for both kk halves, straight from L2 (per-lane addrs;
        // compiler inserts the vmcnt before first use)
        short8 b0[4], b1[4];
        #pragma unroll
        for (int ni = 0; ni < 4; ++ni) {
            const ushort* bp = bG + (size_t)ni * 16 * D_DIM + k0;
            b0[ni] = *(const short8*)(bp);
            b1[ni] = *(const short8*)(bp + 32);
        }

        #pragma unroll
        for (int kk = 0; kk < 2; ++kk) {
            const int swzk = kk ? swz1 : swz0;
            short8 a[8];
            #pragma unroll
            for (int mi = 0; mi < 8; ++mi)
                a[mi] = *(const short8*)(sAb + mi * 16 * 128 + swzk);
            #pragma unroll
            for (int mi = 0; mi < 8; ++mi)
                #pragma unroll
                for (int ni = 0; ni < 4; ++ni)
                    acc[mi][ni] = __builtin_amdgcn_mfma_f32_16x16x32_bf16(
                        a[mi], kk ? b1[ni] : b0[ni], acc[mi][ni], 0, 0, 0);
        }
        __syncthreads();
    }

    // ---- fused epilogue: hyperbolic logits + lane-pair logsumexp ---------
    float* scx = (float*)sA;          // reuse LDS for the cx2 tile
    scx[tid] = cx2g[m0 + tid];        // 256 threads = 256 rows
    __syncthreads();

    const float gam = gamma_p[0];
    const float ex  = expf(2.0f * gam);
    const float ch2 = ex + 1.0f / ex;           // 2*cosh(2*gamma)
    const float sh  = 0.5f * (ex - 1.0f / ex);  // sinh(2*gamma)

    const int  pan = (n0 >> 6) + wn;            // 64-col panel index
    const int  cls = pan * 8 + (lane & 7);
    const bool wrt = ((lane & 8) == 0) && (cls < C_CLS);
    const float w2 = (cls < C_CLS) ? 2.0f * wgl[cls] : 0.0f;

    #pragma unroll
    for (int mi = 0; mi < 8; ++mi) {
        #pragma unroll
        for (int r = 0; r < 4; ++r) {
            const int mloc = wm * 128 + mi * 16 + ((lane >> 4) << 2) + r;
            const float c2   = scx[mloc];
            const float rden = 1.0f / fmaxf(1.0f - c2, 1e-15f);
            const float tc   = ch2 * rden;
            const float tp   = (1.0f + c2) * sh * rden;
            float bk[4];
            #pragma unroll
            for (int ni = 0; ni < 4; ++ni) {
                const float t = fmaf(acc[mi][ni][r], tc, -tp);
                const float u = fmaxf(t + __fsqrt_rn(fmaf(t, t, 1.0f)), 1e-20f);
                bk[ni] = w2 * __logf(u);
            }
            float mx = fmaxf(fmaxf(bk[0], bk[1]), fmaxf(bk[2], bk[3]));
            mx = fmaxf(mx, __shfl_xor(mx, 8));
            float s = __expf(bk[0] - mx) + __expf(bk[1] - mx)
                    + __expf(bk[2] - mx) + __expf(bk[3] - mx);
            s += __shfl_xor(s, 8);
            if (wrt)
                out[(size_t)(m0 + mloc) * C_CLS + cls] = mx + __logf(s);
        }
    }
}

// --- launch ----------------------------------------------------------------

extern "C" void kernel_launch(void* const* d_in, const int* in_sizes, int n_in,
                              void* d_out, int out_size, void* d_ws, size_t ws_size,
                              hipStream_t stream) {
    const float* x     = (const float*)d_in[0];
    const float* wv    = (const float*)d_in[1];
    const float* wg    = (const float*)d_in[2];
    const float* gamma = (const float*)d_in[3];
    float* out = (float*)d_out;

    char* ws = (char*)d_ws;
    ushort* xb  = (ushort*)ws;                                  // 16,777,216 B
    ushort* zb  = (ushort*)(ws + (size_t)B_ROWS * D_DIM * 2);   // 16,515,072 B
    float*  cx2 = (float*)(ws + (size_t)B_ROWS * D_DIM * 2
                              + (size_t)N_PAD * D_DIM * 2);     //     32,768 B

    prep<<<B_ROWS + N_PAD, 256, 0, stream>>>(x, wv, xb, zb, cx2);
    gemm_epi<<<32 * 63, 256, 0, stream>>>(xb, zb, cx2, wg, gamma, out);
}

// Round 13
// 168.486 us; speedup vs baseline: 1.5288x; 1.5288x over previous
//
#include <hip/hip_runtime.h>
#include <hip/hip_bf16.h>
#include <stdint.h>

// Problem dims
#define B_ROWS 8192
#define D_DIM  1024
#define C_CLS  1000
#define K_PROT 8
#define N_PAD  8064          // 63 * 128 zero-padded prototype columns
#define BM2    256
#define BN2    128
#define BKT    64            // K-tile depth (elements)
#define NTI    16            // D_DIM / BKT

typedef __attribute__((ext_vector_type(8))) short  short8;   // 8 bf16
typedef __attribute__((ext_vector_type(4))) float  f32x4;    // MFMA acc

// --- helpers -------------------------------------------------------------

__device__ __forceinline__ ushort f2bf(float f) {
    union { float f; uint32_t u; } v; v.f = f;
    uint32_t u = v.u;
    return (ushort)((u + 0x7fffu + ((u >> 16) & 1u)) >> 16);
}

typedef __attribute__((address_space(1))) void gv_t;
typedef __attribute__((address_space(3))) void lv_t;

__device__ __forceinline__ void gload_lds16(const void* g, void* l) {
    // async global->LDS, 16B/lane; LDS dest = wave-uniform base + lane*16
    __builtin_amdgcn_global_load_lds((gv_t*)g, (lv_t*)l, 16, 0, 0);
}

__device__ __forceinline__ float waveReduceSum(float s) {
    #pragma unroll
    for (int m = 32; m >= 1; m >>= 1) s += __shfl_xor(s, m);
    return s;
}

// --- kernel 1: fused prep -------------------------------------------------
// blocks 0..8191:       x row b -> bf16 + cx2 = sum(x^2)
// blocks 8192..16255:   weight_v -> normalized bf16, PERMUTED + padded
// Column permutation (R6-verified): physical col P: gpan=P>>6 (64-col
// panel), ni=(P>>4)&3, cc=P&15; class = gpan*8 + (cc&7), k = ni+4*(cc>>3)
// -> all 8 k's of a class land in lane pair (lane, lane^8) of the epilogue.

__global__ __launch_bounds__(256) void prep(const float* __restrict__ x,
                                            const float* __restrict__ wv,
                                            ushort* __restrict__ xb,
                                            ushort* __restrict__ zb,
                                            float* __restrict__ cx2) {
    const int t = threadIdx.x;
    __shared__ float red[4];

    if ((int)blockIdx.x < B_ROWS) {
        const int b = blockIdx.x;
        const float4 v = ((const float4*)(x + (size_t)b * D_DIM))[t];
        ushort4 o;
        o.x = f2bf(v.x); o.y = f2bf(v.y); o.z = f2bf(v.z); o.w = f2bf(v.w);
        ((ushort4*)(xb + (size_t)b * D_DIM))[t] = o;
        float s = v.x*v.x + v.y*v.y + v.z*v.z + v.w*v.w;
        s = waveReduceSum(s);
        if ((t & 63) == 0) red[t >> 6] = s;
        __syncthreads();
        if (t == 0) cx2[b] = red[0] + red[1] + red[2] + red[3];
        return;
    }

    const int P    = blockIdx.x - B_ROWS;       // 0..N_PAD-1
    const int gpan = P >> 6;
    const int ni   = (P >> 4) & 3;
    const int cc   = P & 15;
    const int cls  = gpan * 8 + (cc & 7);
    const int k    = ni + ((cc >> 3) << 2);

    if (cls >= C_CLS) {
        ((ushort4*)(zb + (size_t)P * D_DIM))[t] = make_ushort4(0, 0, 0, 0);
        return;
    }
    const int n = cls * K_PROT + k;
    const float4 v = ((const float4*)(wv + (size_t)n * D_DIM))[t];
    float s = v.x*v.x + v.y*v.y + v.z*v.z + v.w*v.w;
    s = waveReduceSum(s);
    if ((t & 63) == 0) red[t >> 6] = s;
    __syncthreads();
    const float n2 = red[0] + red[1] + red[2] + red[3];
    const float rn = 1.0f / fmaxf(sqrtf(n2), 1e-15f);
    ushort4 o;
    o.x = f2bf(v.x * rn); o.y = f2bf(v.y * rn);
    o.z = f2bf(v.z * rn); o.w = f2bf(v.w * rn);
    ((ushort4*)(zb + (size_t)P * D_DIM))[t] = o;
}

// --- kernel 2: 256x128 block, 4 waves (128x64 each) — R6/R11 GEMM ---------
// Best measured structure (R11: 168.2 us bench, ~878 TF effective GEMM,
// MfmaUtil 27.4, 0 bank conflicts = the documented plain-HIP 2-barrier
// structure ceiling). 48 KB LDS -> multi-block/CU; cross-block TLP fills
// barrier stalls (m114). Measured rejections: 1-block/CU pipelines
// (R4/R5/R7/R9/R10: MfmaUtil 21-23), B-direct-from-L2 (R12: latency-bound,
// MfmaUtil 17), fp8/MX (absmax budget).

__global__ __launch_bounds__(256, 2) void gemm_epi(
        const ushort* __restrict__ A,    // [B_ROWS][D_DIM] bf16 (x)
        const ushort* __restrict__ Bz,   // [N_PAD][D_DIM] bf16 (permuted z)
        const float*  __restrict__ cx2g, // [B_ROWS]
        const float*  __restrict__ wgl,  // [C_CLS]
        const float*  __restrict__ gamma_p,
        float*        __restrict__ out)  // [B_ROWS][C_CLS]
{
    __shared__ __attribute__((aligned(16))) ushort sA[BM2 * BKT]; // 32 KB
    __shared__ __attribute__((aligned(16))) ushort sB[BN2 * BKT]; // 16 KB

    const int tid  = threadIdx.x;
    const int lane = tid & 63;
    const int w    = tid >> 6;        // wave 0..3
    const int wm   = w >> 1;          // 0..1 : 128 output rows each
    const int wn   = w & 1;           // 0..1 : 64 output cols each

    // bm fastest: 32 consecutive blocks share one B-panel (256 KB L2-hot)
    const int bm = blockIdx.x & 31;
    const int bn = blockIdx.x >> 5;   // 0..62
    const int m0 = bm * BM2;
    const int n0 = bn * BN2;

    // staging: thread covers row (tid>>3) within each 32-row group; source
    // col-group = (lane&7) ^ (row&7)  [T2 swizzle, source side; row&7=lane>>3]
    const int stCol = ((lane & 7) ^ (lane >> 3)) * 8;
    const ushort* aS = A  + (size_t)(m0 + (tid >> 3)) * D_DIM + stCol;
    const ushort* bS = Bz + (size_t)(n0 + (tid >> 3)) * D_DIM + stCol;

    // fragment read addressing (rows are 128 B; swizzled 16B slot)
    const int swz0 = ((      (lane >> 4) * 16) ^ ((lane & 7) << 4));
    const int swz1 = ((64 + ((lane >> 4) * 16)) ^ ((lane & 7) << 4));
    const char* sAb = (const char*)sA + (wm * 128 + (lane & 15)) * 128;
    const char* sBb = (const char*)sB + (wn * 64  + (lane & 15)) * 128;

    f32x4 acc[8][4];
    #pragma unroll
    for (int mi = 0; mi < 8; ++mi)
        #pragma unroll
        for (int ni = 0; ni < 4; ++ni)
            acc[mi][ni] = (f32x4)(0.0f);

    for (int t = 0; t < NTI; ++t) {
        const int k0 = t * BKT;
        // stage A (8 x 32-row groups) and B (4 x 32-row groups)
        #pragma unroll
        for (int i = 0; i < 8; ++i)
            gload_lds16(aS + (size_t)i * 32 * D_DIM + k0,
                        (char*)sA + i * 4096 + w * 1024);
        #pragma unroll
        for (int i = 0; i < 4; ++i)
            gload_lds16(bS + (size_t)i * 32 * D_DIM + k0,
                        (char*)sB + i * 4096 + w * 1024);
        __syncthreads();

        #pragma unroll
        for (int kk = 0; kk < 2; ++kk) {
            const int swzk = kk ? swz1 : swz0;
            short8 a[8], b[4];
            #pragma unroll
            for (int mi = 0; mi < 8; ++mi)
                a[mi] = *(const short8*)(sAb + mi * 16 * 128 + swzk);
            #pragma unroll
            for (int ni = 0; ni < 4; ++ni)
                b[ni] = *(const short8*)(sBb + ni * 16 * 128 + swzk);
            #pragma unroll
            for (int mi = 0; mi < 8; ++mi)
                #pragma unroll
                for (int ni = 0; ni < 4; ++ni)
                    acc[mi][ni] = __builtin_amdgcn_mfma_f32_16x16x32_bf16(
                        a[mi], b[ni], acc[mi][ni], 0, 0, 0);
        }
        __syncthreads();
    }

    // ---- fused epilogue: hyperbolic logits + lane-pair logsumexp ---------
    float* scx = (float*)sA;          // reuse LDS for the cx2 tile
    scx[tid] = cx2g[m0 + tid];        // 256 threads = 256 rows
    __syncthreads();

    const float gam = gamma_p[0];
    const float ex  = expf(2.0f * gam);
    const float ch2 = ex + 1.0f / ex;           // 2*cosh(2*gamma)
    const float sh  = 0.5f * (ex - 1.0f / ex);  // sinh(2*gamma)

    const int  pan = (n0 >> 6) + wn;            // 64-col panel index
    const int  cls = pan * 8 + (lane & 7);
    const bool wrt = ((lane & 8) == 0) && (cls < C_CLS);
    const float w2 = (cls < C_CLS) ? 2.0f * wgl[cls] : 0.0f;

    #pragma unroll
    for (int mi = 0; mi < 8; ++mi) {
        #pragma unroll
        for (int r = 0; r < 4; ++r) {
            const int mloc = wm * 128 + mi * 16 + ((lane >> 4) << 2) + r;
            const float c2   = scx[mloc];
            const float rden = 1.0f / fmaxf(1.0f - c2, 1e-15f);
            const float tc   = ch2 * rden;
            const float tp   = (1.0f + c2) * sh * rden;
            float bk[4];
            #pragma unroll
            for (int ni = 0; ni < 4; ++ni) {
                const float t = fmaf(acc[mi][ni][r], tc, -tp);
                const float u = fmaxf(t + __fsqrt_rn(fmaf(t, t, 1.0f)), 1e-20f);
                bk[ni] = w2 * __logf(u);
            }
            float mx = fmaxf(fmaxf(bk[0], bk[1]), fmaxf(bk[2], bk[3]));
            mx = fmaxf(mx, __shfl_xor(mx, 8));
            float s = __expf(bk[0] - mx) + __expf(bk[1] - mx)
                    + __expf(bk[2] - mx) + __expf(bk[3] - mx);
            s += __shfl_xor(s, 8);
            if (wrt)
                out[(size_t)(m0 + mloc) * C_CLS + cls] = mx + __logf(s);
        }
    }
}

// --- launch ----------------------------------------------------------------

extern "C" void kernel_launch(void* const* d_in, const int* in_sizes, int n_in,
                              void* d_out, int out_size, void* d_ws, size_t ws_size,
                              hipStream_t stream) {
    const float* x     = (const float*)d_in[0];
    const float* wv    = (const float*)d_in[1];
    const float* wg    = (const float*)d_in[2];
    const float* gamma = (const float*)d_in[3];
    float* out = (float*)d_out;

    char* ws = (char*)d_ws;
    ushort* xb  = (ushort*)ws;                                  // 16,777,216 B
    ushort* zb  = (ushort*)(ws + (size_t)B_ROWS * D_DIM * 2);   // 16,515,072 B
    float*  cx2 = (float*)(ws + (size_t)B_ROWS * D_DIM * 2
                              + (size_t)N_PAD * D_DIM * 2);     //     32,768 B

    prep<<<B_ROWS + N_PAD, 256, 0, stream>>>(x, wv, xb, zb, cx2);
    gemm_epi<<<32 * 63, 256, 0, stream>>>(xb, zb, cx2, wg, gamma, out);
}